// Round 2
// baseline (190.641 us; speedup 1.0000x reference)
//
#include <hip/hip_runtime.h>
#include <stdint.h>

// Simple exponential smoothing, single-pass chained scan w/ decoupled lookback.
// level_t = (1-a)*level_{t-1} + a*y_t, global initial carry s_{-1} = y_0
// (=> level_0 = y_0, uniform recurrence). out[t] = level_t, t in [0, n-2].
//
// Affine pairs (a,b): s_out = a*s_in + b.
// combine(earlier=(a1,b1), later=(a2,b2)) = (a1*a2, a2*b1 + b2).

#define BLOCK 256
#define SEG   64                  // elements per thread
#define VPT   (SEG / 4)           // float4 per thread
#define CHUNK (BLOCK * SEG)       // 16384 elements per tile
#define ROWS  65                  // padded LDS row stride (floats) -> 2-way max

// Inclusive Hillis-Steele scan over BLOCK affine pairs in LDS.
__device__ __forceinline__ void block_scan_affine(float* sa, float* sb, int t) {
#pragma unroll
    for (int off = 1; off < BLOCK; off <<= 1) {
        float pa = 1.0f, pb = 0.0f;
        if (t >= off) { pa = sa[t - off]; pb = sb[t - off]; }
        __syncthreads();
        if (t >= off) {
            float ca = sa[t], cb = sb[t];
            sa[t] = pa * ca;
            sb[t] = fmaf(ca, pb, cb);
        }
        __syncthreads();
    }
}

__global__ __launch_bounds__(BLOCK, 4) void k_scan(
    const float* __restrict__ y, const float* __restrict__ alpha_p,
    float* __restrict__ out,
    int* __restrict__ ticket, int* __restrict__ state,
    float* __restrict__ ppa, float* __restrict__ ppb, float* __restrict__ ple,
    long n, int G)
{
    __shared__ float sa[BLOCK], sb[BLOCK];
    __shared__ float stage[2 * 64 * ROWS];   // 8320 floats = 33280 B
    __shared__ int   s_tile;
    __shared__ float s_carry;

    const int t = threadIdx.x;
    if (t == 0) s_tile = atomicAdd(ticket, 1);   // device-scope; order == start order
    __syncthreads();
    const int  tile  = s_tile;
    const float alpha = alpha_p[0];
    const float oma   = 1.0f - alpha;
    const long tbase = (long)tile * CHUNK;
    const long base  = tbase + (long)t * SEG;
    const bool fullTile = (tbase + CHUNK <= n);

    float4 arr[VPT];
    float a_seg, b_seg;

    if (fullTile) {
        const float4* p = (const float4*)(y + base);
#pragma unroll
        for (int v = 0; v < VPT; ++v) arr[v] = p[v];
        float s = 0.0f;
#pragma unroll
        for (int v = 0; v < VPT; ++v) {
            s = fmaf(oma, s, alpha * arr[v].x);
            s = fmaf(oma, s, alpha * arr[v].y);
            s = fmaf(oma, s, alpha * arr[v].z);
            s = fmaf(oma, s, alpha * arr[v].w);
        }
        b_seg = s;
        a_seg = __powf(oma, (float)SEG);   // uniform; |err| ~ulp, irrelevant vs 2e-2
    } else {
        float a = 1.0f, s = 0.0f;
        for (int k = 0; k < SEG; ++k) {
            long idx = base + k;
            if (idx < n) { s = fmaf(oma, s, alpha * y[idx]); a *= oma; }
        }
        a_seg = a; b_seg = s;
    }

    sa[t] = a_seg; sb[t] = b_seg;
    __syncthreads();
    block_scan_affine(sa, sb, t);          // inclusive; tile agg at [BLOCK-1]

    if (t == 0 && tile > 0) {              // publish partial ASAP
        __hip_atomic_store(&ppa[tile], sa[BLOCK - 1], __ATOMIC_RELAXED, __HIP_MEMORY_SCOPE_AGENT);
        __hip_atomic_store(&ppb[tile], sb[BLOCK - 1], __ATOMIC_RELAXED, __HIP_MEMORY_SCOPE_AGENT);
        __hip_atomic_store(&state[tile], 1, __ATOMIC_RELEASE, __HIP_MEMORY_SCOPE_AGENT);
    }

    // ---- wave-parallel decoupled lookback (wave 0 only) ----
    if (t < 64) {
        float Lstart;
        if (tile == 0) {
            Lstart = y[0];
        } else {
            float Aacc = 1.0f, Bacc = 0.0f;
            int jhi = tile - 1;
            for (;;) {
                int j = jhi - 63 + t;        // lane t reads predecessor j
                float al = 1.0f, bl = 0.0f;  // identity for j < 0
                if (j >= 0) {
                    int st;
                    do {
                        st = __hip_atomic_load(&state[j], __ATOMIC_ACQUIRE, __HIP_MEMORY_SCOPE_AGENT);
                    } while (st == 0);
                    if (st == 2) {
                        al = 0.0f;           // inclusive: affine ignores input
                        bl = __hip_atomic_load(&ple[j], __ATOMIC_RELAXED, __HIP_MEMORY_SCOPE_AGENT);
                    } else {
                        al = __hip_atomic_load(&ppa[j], __ATOMIC_RELAXED, __HIP_MEMORY_SCOPE_AGENT);
                        bl = __hip_atomic_load(&ppb[j], __ATOMIC_RELAXED, __HIP_MEMORY_SCOPE_AGENT);
                    }
                }
                // in-order tree reduce: lane i accumulates compose of lanes [i..63]
#pragma unroll
                for (int off = 1; off < 64; off <<= 1) {
                    float a2 = __shfl_down(al, off);
                    float b2 = __shfl_down(bl, off);
                    if (t + off >= 64) { a2 = 1.0f; b2 = 0.0f; }
                    bl = fmaf(a2, bl, b2);
                    al = al * a2;
                }
                float A = __shfl(al, 0), B = __shfl(bl, 0);
                // acc covers (jhi, tile-1]; window is earlier:
                float nB = fmaf(Aacc, B, Bacc);
                Aacc = Aacc * A;
                Bacc = nB;
                if (Aacc == 0.0f) { Lstart = Bacc; break; }  // hit an inclusive (or underflow: exact enough)
                jhi -= 64;
            }
        }
        if (t == 0) {
            float Lend = fmaf(sa[BLOCK - 1], Lstart, sb[BLOCK - 1]);
            __hip_atomic_store(&ple[tile], Lend, __ATOMIC_RELAXED, __HIP_MEMORY_SCOPE_AGENT);
            __hip_atomic_store(&state[tile], 2, __ATOMIC_RELEASE, __HIP_MEMORY_SCOPE_AGENT);
            s_carry = Lstart;
        }
    }
    __syncthreads();

    const float Lstart = s_carry;
    float ea = 1.0f, eb = 0.0f;
    if (t > 0) { ea = sa[t - 1]; eb = sb[t - 1]; }
    float lvl = fmaf(ea, Lstart, eb);     // level just before this thread's segment

    if (fullTile) {
        // replay in registers, results overwrite arr
#pragma unroll
        for (int v = 0; v < VPT; ++v) {
            float4 q = arr[v], r;
            lvl = fmaf(oma, lvl, alpha * q.x); r.x = lvl;
            lvl = fmaf(oma, lvl, alpha * q.y); r.y = lvl;
            lvl = fmaf(oma, lvl, alpha * q.z); r.z = lvl;
            lvl = fmaf(oma, lvl, alpha * q.w); r.w = lvl;
            arr[v] = r;
        }
        // staged coalesced output: 2 phases x 8192 floats
        const int  wv = t >> 6;
        const int  ln = t & 63;
        const bool lastGuard = (tbase + CHUNK > n - 1);
#pragma unroll
        for (int p = 0; p < 2; ++p) {
            __syncthreads();                       // stage reuse barrier
            if ((wv >> 1) == p) {
                int g = ((wv & 1) << 6) | ln;      // 0..127 within phase
                float* row = &stage[g * ROWS];
#pragma unroll
                for (int v = 0; v < VPT; ++v) {
                    row[4 * v + 0] = arr[v].x;
                    row[4 * v + 1] = arr[v].y;
                    row[4 * v + 2] = arr[v].z;
                    row[4 * v + 3] = arr[v].w;
                }
            }
            __syncthreads();
            const long rbase = tbase + (long)p * 8192;
#pragma unroll
            for (int k = 0; k < 8; ++k) {
                int jj = t + (k << 8);             // float4 idx 0..2047
                int g  = jj >> 4;
                int e  = (jj << 2) & 63;
                const float* row = &stage[g * ROWS + e];
                float4 r;
                r.x = row[0]; r.y = row[1]; r.z = row[2]; r.w = row[3];
                long gi = rbase + 4 * (long)jj;
                if (!lastGuard) {
                    *(float4*)(out + gi) = r;
                } else {
                    if (gi + 4 <= n - 1) {
                        *(float4*)(out + gi) = r;
                    } else {
                        if (gi + 0 < n - 1) out[gi + 0] = r.x;
                        if (gi + 1 < n - 1) out[gi + 1] = r.y;
                        if (gi + 2 < n - 1) out[gi + 2] = r.z;
                        if (gi + 3 < n - 1) out[gi + 3] = r.w;
                    }
                }
            }
        }
    } else {
        // partial tail tile: scalar path
        for (int k = 0; k < SEG; ++k) {
            long idx = base + k;
            if (idx < n) {
                lvl = fmaf(oma, lvl, alpha * y[idx]);
                if (idx < n - 1) out[idx] = lvl;
            }
        }
    }
}

extern "C" void kernel_launch(void* const* d_in, const int* in_sizes, int n_in,
                              void* d_out, int out_size, void* d_ws, size_t ws_size,
                              hipStream_t stream) {
    const float* y     = (const float*)d_in[0];
    const float* alpha = (const float*)d_in[1];
    float* out = (float*)d_out;
    const long n = (long)in_sizes[0];
    const int  G = (int)((n + CHUNK - 1) / CHUNK);   // 1024 for n = 2^24

    // ws layout: [0..16) ticket (+pad) | state[G] | ppa[G] | ppb[G] | ple[G]
    char* ws = (char*)d_ws;
    int*   ticket = (int*)ws;
    int*   state  = (int*)(ws + 16);
    float* ppa    = (float*)(ws + 16 + 4 * (size_t)G);
    float* ppb    = (float*)(ws + 16 + 8 * (size_t)G);
    float* ple    = (float*)(ws + 16 + 12 * (size_t)G);

    // zero ticket + state flags (poisoned to 0xAA before each timed call)
    hipMemsetAsync(d_ws, 0, 16 + 4 * (size_t)G, stream);

    k_scan<<<G, BLOCK, 0, stream>>>(y, alpha, out, ticket, state, ppa, ppb, ple, n, G);
}

// Round 3
// 130.153 us; speedup vs baseline: 1.4648x; 1.4648x over previous
//
#include <hip/hip_runtime.h>
#include <stdint.h>

// Simple exponential smoothing: level_t = (1-a)*level_{t-1} + a*y_t,
// level_0 = y_0 pinned via global initial carry s_{-1} = y_0.
// out[t] = level_t for t in [0, n-2].
//
// 3-pass reduce-then-scan (no cross-block atomics — agent-scope acquire/release
// spin-polling cost ~80us on MI355X due to cross-XCD L2 coherence ops; R2 post-mortem).
// Affine pairs (a,b): s_out = a*s_in + b.
// combine(earlier=(a1,b1), later=(a2,b2)) = (a1*a2, a2*b1 + b2).

#define BLOCK 256
#define SEG   64                  // elements per thread
#define VPT   (SEG / 4)           // float4 per thread
#define CHUNK (BLOCK * SEG)       // 16384 elements per block
#define ROWS  65                  // padded LDS row stride -> max 2-way bank alias (free)

// Inclusive Hillis-Steele scan over BLOCK affine pairs in LDS.
__device__ __forceinline__ void block_scan_affine(float* sa, float* sb, int t) {
#pragma unroll
    for (int off = 1; off < BLOCK; off <<= 1) {
        float pa = 1.0f, pb = 0.0f;
        if (t >= off) { pa = sa[t - off]; pb = sb[t - off]; }
        __syncthreads();
        if (t >= off) {
            float ca = sa[t], cb = sb[t];
            sa[t] = pa * ca;
            sb[t] = fmaf(ca, pb, cb);
        }
        __syncthreads();
    }
}

// Pass 1: per-block affine aggregate.
__global__ __launch_bounds__(BLOCK) void k_block_agg(
    const float* __restrict__ y, const float* __restrict__ alpha_p,
    float* __restrict__ aggA, float* __restrict__ aggB, long n)
{
    const int t = threadIdx.x;
    const long base = (long)blockIdx.x * CHUNK + (long)t * SEG;
    const float alpha = alpha_p[0];
    const float oma = 1.0f - alpha;

    float a = 1.0f, s = 0.0f;
    if (base + SEG <= n) {
        const float4* p = (const float4*)(y + base);
#pragma unroll
        for (int v = 0; v < VPT; ++v) {
            float4 q = p[v];
            s = fmaf(oma, s, alpha * q.x);
            s = fmaf(oma, s, alpha * q.y);
            s = fmaf(oma, s, alpha * q.z);
            s = fmaf(oma, s, alpha * q.w);
            a *= oma; a *= oma; a *= oma; a *= oma;
        }
    } else {
        for (int k = 0; k < SEG; ++k) {
            long idx = base + k;
            if (idx < n) { s = fmaf(oma, s, alpha * y[idx]); a *= oma; }
        }
    }

    __shared__ float sa[BLOCK], sb[BLOCK];
    sa[t] = a; sb[t] = s;
    __syncthreads();
    block_scan_affine(sa, sb, t);
    if (t == BLOCK - 1) {
        aggA[blockIdx.x] = sa[t];
        aggB[blockIdx.x] = sb[t];
    }
}

// Pass 2: scan the G block aggregates -> per-block carry (level before block g).
__global__ __launch_bounds__(BLOCK) void k_carry_scan(
    const float* __restrict__ aggA, const float* __restrict__ aggB,
    const float* __restrict__ y, float* __restrict__ carry, int G)
{
    const int t = threadIdx.x;
    const int items = (G + BLOCK - 1) / BLOCK;
    const float y0 = y[0];

    float ta = 1.0f, tb = 0.0f;
    for (int j = 0; j < items; ++j) {
        int g = t * items + j;
        if (g < G) {
            float ca = aggA[g], cb = aggB[g];
            float na = ta * ca;
            float nb = fmaf(ca, tb, cb);
            ta = na; tb = nb;
        }
    }

    __shared__ float sa[BLOCK], sb[BLOCK];
    sa[t] = ta; sb[t] = tb;
    __syncthreads();
    block_scan_affine(sa, sb, t);

    float ea = 1.0f, eb = 0.0f;
    if (t > 0) { ea = sa[t - 1]; eb = sb[t - 1]; }
    for (int j = 0; j < items; ++j) {
        int g = t * items + j;
        if (g < G) {
            carry[g] = fmaf(ea, y0, eb);
            float ca = aggA[g], cb = aggB[g];
            float na = ea * ca;
            float nb = fmaf(ca, eb, cb);
            ea = na; eb = nb;
        }
    }
}

// Pass 3: recompute thread aggregates from register-cached data, block scan,
// replay, and emit via LDS-staged fully-coalesced float4 stores.
__global__ __launch_bounds__(BLOCK, 4) void k_emit(
    const float* __restrict__ y, const float* __restrict__ alpha_p,
    const float* __restrict__ carry, float* __restrict__ out, long n)
{
    __shared__ float sa[BLOCK], sb[BLOCK];
    __shared__ float stage[2 * 64 * ROWS];   // 33280 B; +2KB sa/sb -> 4 blocks/CU

    const int t = threadIdx.x;
    const long tbase = (long)blockIdx.x * CHUNK;
    const long base  = tbase + (long)t * SEG;
    const float alpha = alpha_p[0];
    const float oma   = 1.0f - alpha;
    const float c     = carry[blockIdx.x];   // prefetch early (ready since pass 2)
    const bool fullTile = (tbase + CHUNK <= n);

    float4 arr[VPT];
    float a_seg, b_seg;

    if (fullTile) {
        const float4* p = (const float4*)(y + base);
#pragma unroll
        for (int v = 0; v < VPT; ++v) arr[v] = p[v];
        float s = 0.0f;
#pragma unroll
        for (int v = 0; v < VPT; ++v) {
            s = fmaf(oma, s, alpha * arr[v].x);
            s = fmaf(oma, s, alpha * arr[v].y);
            s = fmaf(oma, s, alpha * arr[v].z);
            s = fmaf(oma, s, alpha * arr[v].w);
        }
        b_seg = s;
        a_seg = __powf(oma, (float)SEG);     // |err| ~ulp, irrelevant vs 2e-2 threshold
    } else {
        float a = 1.0f, s = 0.0f;
        for (int k = 0; k < SEG; ++k) {
            long idx = base + k;
            if (idx < n) { s = fmaf(oma, s, alpha * y[idx]); a *= oma; }
        }
        a_seg = a; b_seg = s;
    }

    sa[t] = a_seg; sb[t] = b_seg;
    __syncthreads();
    block_scan_affine(sa, sb, t);

    float ea = 1.0f, eb = 0.0f;
    if (t > 0) { ea = sa[t - 1]; eb = sb[t - 1]; }
    float lvl = fmaf(ea, c, eb);            // level just before this thread's segment

    if (fullTile) {
        // replay in registers, results overwrite arr
#pragma unroll
        for (int v = 0; v < VPT; ++v) {
            float4 q = arr[v], r;
            lvl = fmaf(oma, lvl, alpha * q.x); r.x = lvl;
            lvl = fmaf(oma, lvl, alpha * q.y); r.y = lvl;
            lvl = fmaf(oma, lvl, alpha * q.z); r.z = lvl;
            lvl = fmaf(oma, lvl, alpha * q.w); r.w = lvl;
            arr[v] = r;
        }
        // staged coalesced output: 2 phases x 8192 floats
        const int  wv = t >> 6;
        const int  ln = t & 63;
        const bool lastGuard = (tbase + CHUNK > n - 1);
#pragma unroll
        for (int p = 0; p < 2; ++p) {
            __syncthreads();                       // stage reuse barrier
            if ((wv >> 1) == p) {
                int g = ((wv & 1) << 6) | ln;      // row 0..127 within phase
                float* row = &stage[g * ROWS];
#pragma unroll
                for (int v = 0; v < VPT; ++v) {
                    row[4 * v + 0] = arr[v].x;
                    row[4 * v + 1] = arr[v].y;
                    row[4 * v + 2] = arr[v].z;
                    row[4 * v + 3] = arr[v].w;
                }
            }
            __syncthreads();
            const long rbase = tbase + (long)p * 8192;
#pragma unroll
            for (int k = 0; k < 8; ++k) {
                int jj = t + (k << 8);             // float4 idx 0..2047
                int g  = jj >> 4;
                int e  = (jj << 2) & 63;
                const float* row = &stage[g * ROWS + e];
                float4 r;
                r.x = row[0]; r.y = row[1]; r.z = row[2]; r.w = row[3];
                long gi = rbase + 4 * (long)jj;
                if (!lastGuard) {
                    *(float4*)(out + gi) = r;
                } else {
                    if (gi + 4 <= n - 1) {
                        *(float4*)(out + gi) = r;
                    } else {
                        if (gi + 0 < n - 1) out[gi + 0] = r.x;
                        if (gi + 1 < n - 1) out[gi + 1] = r.y;
                        if (gi + 2 < n - 1) out[gi + 2] = r.z;
                        if (gi + 3 < n - 1) out[gi + 3] = r.w;
                    }
                }
            }
        }
    } else {
        // partial tail tile: scalar path
        for (int k = 0; k < SEG; ++k) {
            long idx = base + k;
            if (idx < n) {
                lvl = fmaf(oma, lvl, alpha * y[idx]);
                if (idx < n - 1) out[idx] = lvl;
            }
        }
    }
}

extern "C" void kernel_launch(void* const* d_in, const int* in_sizes, int n_in,
                              void* d_out, int out_size, void* d_ws, size_t ws_size,
                              hipStream_t stream) {
    const float* y     = (const float*)d_in[0];
    const float* alpha = (const float*)d_in[1];
    float* out = (float*)d_out;
    const long n = (long)in_sizes[0];
    const int  G = (int)((n + CHUNK - 1) / CHUNK);   // 1024 for n = 2^24

    float* aggA  = (float*)d_ws;       // G floats
    float* aggB  = aggA + G;           // G floats
    float* carry = aggB + G;           // G floats (12 KiB total, fully written pre-read)

    k_block_agg<<<G, BLOCK, 0, stream>>>(y, alpha, aggA, aggB, n);
    k_carry_scan<<<1, BLOCK, 0, stream>>>(aggA, aggB, y, carry, G);
    k_emit<<<G, BLOCK, 0, stream>>>(y, alpha, carry, out, n);
}

// Round 5
// 129.196 us; speedup vs baseline: 1.4756x; 1.0074x over previous
//
#include <hip/hip_runtime.h>
#include <stdint.h>

// Simple exponential smoothing: level_t = (1-a)*level_{t-1} + a*y_t,
// level_0 = y_0 pinned via global initial carry s_{-1} = y_0.
// out[t] = level_t for t in [0, n-2].
//
// 2-pass reduce-then-scan:
//   pass 1: per-block affine aggregate -> aggA/aggB[G]
//   pass 2 (fused): each block redundantly scans the G aggregates (8KB,
//           L2-resident) to get its own carry, then replays its tile from
//           register-cached input and emits via LDS-staged coalesced stores
//           (R3-verified: WRITE_SIZE 206MB -> 65.7MB).
// No cross-block atomics (R2: agent-scope spin cost ~80us) and no cooperative
// launch (R4: rejected under graph capture -> output never written).
//
// Affine pairs (a,b): s_out = a*s_in + b.
// combine(earlier=(a1,b1), later=(a2,b2)) = (a1*a2, a2*b1 + b2).

#define BLOCK 256
#define SEG   64                  // elements per thread
#define VPT   (SEG / 4)           // float4 per thread
#define CHUNK (BLOCK * SEG)       // 16384 elements per block
#define ROWS  65                  // padded LDS row stride -> max 2-way bank alias (free)

// Inclusive Hillis-Steele scan over BLOCK affine pairs in LDS.
__device__ __forceinline__ void block_scan_affine(float* sa, float* sb, int t) {
#pragma unroll
    for (int off = 1; off < BLOCK; off <<= 1) {
        float pa = 1.0f, pb = 0.0f;
        if (t >= off) { pa = sa[t - off]; pb = sb[t - off]; }
        __syncthreads();
        if (t >= off) {
            float ca = sa[t], cb = sb[t];
            sa[t] = pa * ca;
            sb[t] = fmaf(ca, pb, cb);
        }
        __syncthreads();
    }
}

// Pass 1: per-block affine aggregate.
__global__ __launch_bounds__(BLOCK) void k_block_agg(
    const float* __restrict__ y, const float* __restrict__ alpha_p,
    float* __restrict__ aggA, float* __restrict__ aggB, long n)
{
    const int t = threadIdx.x;
    const long base = (long)blockIdx.x * CHUNK + (long)t * SEG;
    const float alpha = alpha_p[0];
    const float oma = 1.0f - alpha;

    float a = 1.0f, s = 0.0f;
    if (base + SEG <= n) {
        const float4* p = (const float4*)(y + base);
#pragma unroll
        for (int v = 0; v < VPT; ++v) {
            float4 q = p[v];
            s = fmaf(oma, s, alpha * q.x);
            s = fmaf(oma, s, alpha * q.y);
            s = fmaf(oma, s, alpha * q.z);
            s = fmaf(oma, s, alpha * q.w);
        }
        a = __powf(oma, (float)SEG);
    } else {
        for (int k = 0; k < SEG; ++k) {
            long idx = base + k;
            if (idx < n) { s = fmaf(oma, s, alpha * y[idx]); a *= oma; }
        }
    }

    __shared__ float sa[BLOCK], sb[BLOCK];
    sa[t] = a; sb[t] = s;
    __syncthreads();
    block_scan_affine(sa, sb, t);
    if (t == BLOCK - 1) {
        aggA[blockIdx.x] = sa[t];
        aggB[blockIdx.x] = sb[t];
    }
}

// Pass 2 (fused): per-block carry from redundant aggregate scan, then replay
// from register-cached input and emit via LDS-staged coalesced float4 stores.
__global__ __launch_bounds__(BLOCK, 4) void k_emit_fused(
    const float* __restrict__ y, const float* __restrict__ alpha_p,
    const float* __restrict__ aggA, const float* __restrict__ aggB,
    float* __restrict__ out, long n, int G)
{
    __shared__ float sa[BLOCK], sb[BLOCK];
    __shared__ float stage[2 * 64 * ROWS];   // 33280 B; ~35.4 KB total -> 4 blocks/CU
    __shared__ float s_carry;

    const int t = threadIdx.x;
    const int tile = blockIdx.x;
    const float alpha = alpha_p[0];
    const float oma   = 1.0f - alpha;
    const long tbase = (long)tile * CHUNK;
    const long base  = tbase + (long)t * SEG;
    const bool fullTile = (tbase + CHUNK <= n);
    const float y0 = y[0];

    // ---- phase A: load tile into registers, per-thread affine reduce ----
    float4 arr[VPT];
    float a_seg, b_seg;
    if (fullTile) {
        const float4* p = (const float4*)(y + base);
#pragma unroll
        for (int v = 0; v < VPT; ++v) arr[v] = p[v];
        float s = 0.0f;
#pragma unroll
        for (int v = 0; v < VPT; ++v) {
            s = fmaf(oma, s, alpha * arr[v].x);
            s = fmaf(oma, s, alpha * arr[v].y);
            s = fmaf(oma, s, alpha * arr[v].z);
            s = fmaf(oma, s, alpha * arr[v].w);
        }
        b_seg = s;
        a_seg = __powf(oma, (float)SEG);     // |err| ~ulp, irrelevant vs 2e-2 threshold
    } else {
        float a = 1.0f, s = 0.0f;
        for (int k = 0; k < SEG; ++k) {
            long idx = base + k;
            if (idx < n) { s = fmaf(oma, s, alpha * y[idx]); a *= oma; }
        }
        a_seg = a; b_seg = s;
    }

    sa[t] = a_seg; sb[t] = b_seg;
    __syncthreads();
    block_scan_affine(sa, sb, t);

    // per-thread exclusive prefix within tile (before sa/sb are reused)
    float ea_th = 1.0f, eb_th = 0.0f;
    if (t > 0) { ea_th = sa[t - 1]; eb_th = sb[t - 1]; }

    // ---- phase B: redundant scan of G aggregates -> this tile's carry ----
    const int items = (G + BLOCK - 1) / BLOCK;       // 4 for G=1024
    {
        float ta = 1.0f, tb = 0.0f;
        for (int j = 0; j < items; ++j) {
            int g = t * items + j;
            if (g < G) {
                float ca = aggA[g], cb = aggB[g];
                tb = fmaf(ca, tb, cb);
                ta *= ca;
            }
        }
        __syncthreads();             // ea_th/eb_th reads done; safe to reuse sa/sb
        sa[t] = ta; sb[t] = tb;
        __syncthreads();
        block_scan_affine(sa, sb, t);

        const int q = tile / items;          // owning thread for this tile's prefix
        if (t == q) {
            float ea = (q > 0) ? sa[q - 1] : 1.0f;
            float eb = (q > 0) ? sb[q - 1] : 0.0f;
            const int r = tile - q * items;  // remaining aggregates [q*items, tile)
            for (int j = 0; j < r; ++j) {
                int g = q * items + j;
                float ca = aggA[g], cb = aggB[g];
                eb = fmaf(ca, eb, cb);
                ea *= ca;
            }
            s_carry = fmaf(ea, y0, eb);      // level just before this tile
        }
        __syncthreads();
    }

    float lvl = fmaf(ea_th, s_carry, eb_th); // level just before this thread's segment

    // ---- phase C: replay from registers, staged coalesced output ----
    if (fullTile) {
#pragma unroll
        for (int v = 0; v < VPT; ++v) {
            float4 q4 = arr[v], r;
            lvl = fmaf(oma, lvl, alpha * q4.x); r.x = lvl;
            lvl = fmaf(oma, lvl, alpha * q4.y); r.y = lvl;
            lvl = fmaf(oma, lvl, alpha * q4.z); r.z = lvl;
            lvl = fmaf(oma, lvl, alpha * q4.w); r.w = lvl;
            arr[v] = r;
        }
        const int  wv = t >> 6;
        const int  ln = t & 63;
        const bool lastGuard = (tbase + CHUNK > n - 1);
#pragma unroll
        for (int p = 0; p < 2; ++p) {
            __syncthreads();                       // stage reuse barrier
            if ((wv >> 1) == p) {
                int g = ((wv & 1) << 6) | ln;      // row 0..127 within phase
                float* row = &stage[g * ROWS];
#pragma unroll
                for (int v = 0; v < VPT; ++v) {
                    row[4 * v + 0] = arr[v].x;
                    row[4 * v + 1] = arr[v].y;
                    row[4 * v + 2] = arr[v].z;
                    row[4 * v + 3] = arr[v].w;
                }
            }
            __syncthreads();
            const long rbase = tbase + (long)p * 8192;
#pragma unroll
            for (int k = 0; k < 8; ++k) {
                int jj = t + (k << 8);             // float4 idx 0..2047
                int g  = jj >> 4;
                int e  = (jj << 2) & 63;
                const float* row = &stage[g * ROWS + e];
                float4 r;
                r.x = row[0]; r.y = row[1]; r.z = row[2]; r.w = row[3];
                long gi = rbase + 4 * (long)jj;
                if (!lastGuard) {
                    *(float4*)(out + gi) = r;
                } else {
                    if (gi + 4 <= n - 1) {
                        *(float4*)(out + gi) = r;
                    } else {
                        if (gi + 0 < n - 1) out[gi + 0] = r.x;
                        if (gi + 1 < n - 1) out[gi + 1] = r.y;
                        if (gi + 2 < n - 1) out[gi + 2] = r.z;
                        if (gi + 3 < n - 1) out[gi + 3] = r.w;
                    }
                }
            }
        }
    } else {
        for (int k = 0; k < SEG; ++k) {
            long idx = base + k;
            if (idx < n) {
                lvl = fmaf(oma, lvl, alpha * y[idx]);
                if (idx < n - 1) out[idx] = lvl;
            }
        }
    }
}

extern "C" void kernel_launch(void* const* d_in, const int* in_sizes, int n_in,
                              void* d_out, int out_size, void* d_ws, size_t ws_size,
                              hipStream_t stream) {
    const float* y     = (const float*)d_in[0];
    const float* alpha = (const float*)d_in[1];
    float* out = (float*)d_out;
    const long n = (long)in_sizes[0];
    const int  G = (int)((n + CHUNK - 1) / CHUNK);   // 1024 for n = 2^24

    float* aggA = (float*)d_ws;        // G floats
    float* aggB = aggA + G;            // G floats (fully written before read; no zeroing)

    k_block_agg<<<G, BLOCK, 0, stream>>>(y, alpha, aggA, aggB, n);
    k_emit_fused<<<G, BLOCK, 0, stream>>>(y, alpha, aggA, aggB, out, n, G);
}